// Round 1
// baseline (64.084 us; speedup 1.0000x reference)
//
#include <hip/hip_runtime.h>
#include <math.h>

#define NB 32       // batch
#define NI 32       // input capsules
#define NA 16       // input atoms
#define NOD 10      // output dim (classes)
#define NOA 16      // output atoms
#define NK (NOD*NOA)   // 160
#define NHW 144
#define NROUT 3
#define P 2            // pixels per block
#define NTHREADS 256

__global__ __launch_bounds__(NTHREADS)
void capsule_routing_kernel(const float* __restrict__ x,      // [B,I,A,HW]
                            const float* __restrict__ weight, // [I,A,K]
                            const float* __restrict__ bias,   // [K]
                            float* __restrict__ out)          // [B,OD,OA,HW] = [B,K,HW]
{
    __shared__ float sx[NI][NA][P];       // x slice, pixel-innermost
    __shared__ float sv[P][NI][NK];       // votes
    __shared__ float slog[P][NI][NOD];    // routing logits
    __shared__ float srt[P][NI][NOD];     // softmax(route)
    __shared__ float sact[P][NK];         // preact / activation

    const int bk  = blockIdx.x;           // 0 .. B*HW/P-1 = 2303
    const int b   = bk / (NHW / P);       // HW/P = 72
    const int hw0 = (bk % (NHW / P)) * P;
    const int tid = threadIdx.x;

    // ---- 1) load x slice (float2 across the two pixels), zero logits ----
    for (int j = tid; j < NI * NA; j += NTHREADS) {
        const int i = j >> 4;          // / NA
        const int a = j & (NA - 1);    // % NA
        const float2 v = *reinterpret_cast<const float2*>(
            x + (size_t)((b * NI + i) * NA + a) * NHW + hw0);
        sx[i][a][0] = v.x;
        sx[i][a][1] = v.y;
    }
    {
        float* lf = &slog[0][0][0];
        for (int j = tid; j < P * NI * NOD; j += NTHREADS) lf[j] = 0.0f;
    }
    __syncthreads();

    // ---- 2) votes[i][k] = sum_a x[i][a] * w[i][a][k], both pixels ----
    for (int j = tid; j < NI * NK; j += NTHREADS) {      // 20 iters
        const int i = j / NK;
        const int k = j - i * NK;
        const float* wp = weight + (size_t)i * NA * NK + k;
        float acc0 = 0.0f, acc1 = 0.0f;
#pragma unroll
        for (int a = 0; a < NA; ++a) {
            const float wv = wp[a * NK];
            acc0 = fmaf(sx[i][a][0], wv, acc0);
            acc1 = fmaf(sx[i][a][1], wv, acc1);
        }
        sv[0][i][k] = acc0;
        sv[1][i][k] = acc1;
    }
    __syncthreads();

    // ---- 3) dynamic routing ----
    for (int it = 0; it < NROUT; ++it) {
        // softmax over od for each (p, i): P*I = 64 rows
        if (tid < P * NI) {
            const int p = tid / NI;
            const int i = tid - p * NI;
            float m = slog[p][i][0];
#pragma unroll
            for (int od = 1; od < NOD; ++od) m = fmaxf(m, slog[p][i][od]);
            float s = 0.0f;
#pragma unroll
            for (int od = 0; od < NOD; ++od) {
                const float e = expf(slog[p][i][od] - m);
                srt[p][i][od] = e;
                s += e;
            }
            const float inv = 1.0f / s;
#pragma unroll
            for (int od = 0; od < NOD; ++od) srt[p][i][od] *= inv;
        }
        __syncthreads();

        // preact[p][k] = bias[k] + sum_i route[p][i][od(k)] * votes[p][i][k]
        for (int j = tid; j < P * NK; j += NTHREADS) {   // 320 outputs
            const int p = j / NK;
            const int k = j - p * NK;
            const int od = k >> 4;   // / NOA
            float acc = bias[k];
#pragma unroll 8
            for (int i = 0; i < NI; ++i)
                acc = fmaf(srt[p][i][od], sv[p][i][k], acc);
            sact[p][k] = acc;
        }
        __syncthreads();

        // squash per (p, od): act = pre * |pre| / (1 + |pre|^2)
        if (tid < P * NOD) {
            const int p = tid / NOD;
            const int od = tid - p * NOD;
            float ss = 0.0f;
#pragma unroll
            for (int oa = 0; oa < NOA; ++oa) {
                const float v = sact[p][od * NOA + oa];
                ss = fmaf(v, v, ss);
            }
            const float scale = sqrtf(ss) / (1.0f + ss);
#pragma unroll
            for (int oa = 0; oa < NOA; ++oa) sact[p][od * NOA + oa] *= scale;
        }
        __syncthreads();

        if (it < NROUT - 1) {
            // logits[p][i][od] += sum_oa votes[p][i][od*16+oa] * act[p][od*16+oa]
            for (int j = tid; j < P * NI * NOD; j += NTHREADS) {  // 640 outputs
                const int p = j / (NI * NOD);
                const int r = j - p * (NI * NOD);
                const int i = r / NOD;
                const int od = r - i * NOD;
                float acc = 0.0f;
#pragma unroll
                for (int oa = 0; oa < NOA; ++oa)
                    acc = fmaf(sv[p][i][od * NOA + oa], sact[p][od * NOA + oa], acc);
                slog[p][i][od] += acc;
            }
            __syncthreads();
        }
    }

    // ---- 4) write activation: out[(b*K + k)*HW + hw0 + p] ----
    if (tid < NK) {
        const float2 v = make_float2(sact[0][tid], sact[1][tid]);
        *reinterpret_cast<float2*>(out + (size_t)(b * NK + tid) * NHW + hw0) = v;
    }
}

extern "C" void kernel_launch(void* const* d_in, const int* in_sizes, int n_in,
                              void* d_out, int out_size, void* d_ws, size_t ws_size,
                              hipStream_t stream) {
    const float* x      = (const float*)d_in[0];
    const float* weight = (const float*)d_in[1];
    const float* bias   = (const float*)d_in[2];
    float* out          = (float*)d_out;

    const int nblocks = NB * (NHW / P);   // 32 * 72 = 2304
    capsule_routing_kernel<<<nblocks, NTHREADS, 0, stream>>>(x, weight, bias, out);
}

// Round 2
// 52.914 us; speedup vs baseline: 1.2111x; 1.2111x over previous
//
#include <hip/hip_runtime.h>
#include <math.h>

#define NB 32       // batch
#define NI 32       // input capsules
#define NA 16       // input atoms
#define NOD 10      // output dim (classes)
#define NOA 16      // output atoms
#define NK (NOD*NOA)   // 160
#define NHW 144
#define NROUT 3
#define P 2            // pixels per block
#define NTHREADS 512
#define SVLD (NK + 1)  // 161: padded row stride so bank=(i+16*od+oa)%32

__global__ __launch_bounds__(NTHREADS)
void capsule_routing_kernel(const float* __restrict__ x,      // [B,I,A,HW]
                            const float* __restrict__ weight, // [I,A,K]
                            const float* __restrict__ bias,   // [K]
                            float* __restrict__ out)          // [B,K,HW]
{
    __shared__ float sx[NI][NA][P];          // 4 KB
    __shared__ float sv[P * NI * SVLD];      // 41.2 KB, padded votes
    __shared__ float slog[P][NI][NOD];       // 2.5 KB
    __shared__ float srt[P][NI][NOD];        // 2.5 KB
    __shared__ float sact[P][NOD][NOA + 1];  // 1.4 KB, od -> distinct banks

    const int bk  = blockIdx.x;              // 0 .. B*HW/P-1 = 2303
    const int b   = bk / (NHW / P);
    const int hw0 = (bk % (NHW / P)) * P;
    const int tid = threadIdx.x;

#define SV(p, i, k) sv[((p) * NI + (i)) * SVLD + (k)]

    // ---- 1) load x slice (float2 across the two pixels), zero logits ----
    if (tid < NI * NA) {                     // exactly 512 tasks
        const int i = tid >> 4;
        const int a = tid & (NA - 1);
        const float2 v = *reinterpret_cast<const float2*>(
            x + (size_t)((b * NI + i) * NA + a) * NHW + hw0);
        sx[i][a][0] = v.x;
        sx[i][a][1] = v.y;
    }
    {
        float* lf = &slog[0][0][0];
        for (int j = tid; j < P * NI * NOD; j += NTHREADS) lf[j] = 0.0f;
    }
    __syncthreads();

    // ---- 2) votes[i][k] = sum_a x[i][a] * w[i][a][k], both pixels ----
    for (int j = tid; j < NI * NK; j += NTHREADS) {      // 10 iters
        const int i = j / NK;
        const int k = j - i * NK;
        const float* wp = weight + (size_t)i * NA * NK + k;
        float acc0 = 0.0f, acc1 = 0.0f;
#pragma unroll
        for (int a = 0; a < NA; ++a) {
            const float wv = wp[a * NK];
            acc0 = fmaf(sx[i][a][0], wv, acc0);
            acc1 = fmaf(sx[i][a][1], wv, acc1);
        }
        SV(0, i, k) = acc0;
        SV(1, i, k) = acc1;
    }
    __syncthreads();

    // ---- 3) dynamic routing ----
    for (int it = 0; it < NROUT; ++it) {
        // softmax over od for each (p, i): 64 rows
        if (tid < P * NI) {
            const int p = tid >> 5;
            const int i = tid & 31;
            float m = slog[p][i][0];
#pragma unroll
            for (int od = 1; od < NOD; ++od) m = fmaxf(m, slog[p][i][od]);
            float s = 0.0f;
            float e[NOD];
#pragma unroll
            for (int od = 0; od < NOD; ++od) {
                e[od] = __expf(slog[p][i][od] - m);
                s += e[od];
            }
            const float inv = 1.0f / s;
#pragma unroll
            for (int od = 0; od < NOD; ++od) srt[p][i][od] = e[od] * inv;
        }
        __syncthreads();

        // preact + fused squash: 320 tasks, one (p,k) per thread
        if (tid < P * NK) {
            const int p  = tid / NK;
            const int k  = tid - p * NK;
            const int od = k >> 4;
            const int oa = k & (NOA - 1);
            float acc = bias[k];
#pragma unroll 8
            for (int i = 0; i < NI; ++i)
                acc = fmaf(srt[p][i][od], SV(p, i, k), acc);
            // squash: 16-lane reduction over the oa-group (lanes aligned)
            float ss = acc * acc;
#pragma unroll
            for (int m = 1; m < NOA; m <<= 1)
                ss += __shfl_xor(ss, m, NOA);
            const float scale = sqrtf(ss) / (1.0f + ss);
            sact[p][od][oa] = acc * scale;
        }
        __syncthreads();

        if (it < NROUT - 1) {
            // logits[p][i][od] += sum_oa votes[p][i][od*16+oa]*act[p][od][oa]
            // 640 tasks, i-innermost so 32 lanes span all 32 banks
            for (int j = tid; j < P * NI * NOD; j += NTHREADS) {
                const int p  = j / (NI * NOD);
                const int r  = j - p * (NI * NOD);
                const int od = r >> 5;
                const int i  = r & 31;
                float acc = 0.0f;
#pragma unroll
                for (int oa = 0; oa < NOA; ++oa)
                    acc = fmaf(SV(p, i, od * NOA + oa), sact[p][od][oa], acc);
                slog[p][i][od] += acc;
            }
            __syncthreads();
        }
    }

    // ---- 4) write activation: out[(b*K + k)*HW + hw0 + p] ----
    __syncthreads();
    if (tid < NK) {
        const int od = tid >> 4;
        const int oa = tid & (NOA - 1);
        const float2 v = make_float2(sact[0][od][oa], sact[1][od][oa]);
        *reinterpret_cast<float2*>(out + (size_t)(b * NK + tid) * NHW + hw0) = v;
    }
}

extern "C" void kernel_launch(void* const* d_in, const int* in_sizes, int n_in,
                              void* d_out, int out_size, void* d_ws, size_t ws_size,
                              hipStream_t stream) {
    const float* x      = (const float*)d_in[0];
    const float* weight = (const float*)d_in[1];
    const float* bias   = (const float*)d_in[2];
    float* out          = (float*)d_out;

    const int nblocks = NB * (NHW / P);   // 2304
    capsule_routing_kernel<<<nblocks, NTHREADS, 0, stream>>>(x, weight, bias, out);
}

// Round 3
// 47.918 us; speedup vs baseline: 1.3374x; 1.1043x over previous
//
#include <hip/hip_runtime.h>
#include <math.h>

#define NB 32       // batch
#define NI 32       // input capsules
#define NA 16       // input atoms
#define NOD 10      // output dim
#define NOA 16      // output atoms
#define NK 160      // NOD*NOA
#define NHW 144
#define NROUT 3
#define P 2         // pixels per block
#define NTHREADS 512
#define SVLD 168    // bf16 elems per sv row (336 B, 21 b128-slots -> spread banks)

// manual bf16 RNE pack / unpack (bit ops compile to 1-3 VALU ops)
__device__ __forceinline__ unsigned short f2bf(float f) {
    unsigned b = __builtin_bit_cast(unsigned, f);
    b += 0x7fffu + ((b >> 16) & 1u);
    return (unsigned short)(b >> 16);
}
__device__ __forceinline__ float bf2f(unsigned short u) {
    return __builtin_bit_cast(float, (unsigned)u << 16);
}
__device__ __forceinline__ float bf_lo(unsigned d) {
    return __builtin_bit_cast(float, d << 16);
}
__device__ __forceinline__ float bf_hi(unsigned d) {
    return __builtin_bit_cast(float, d & 0xffff0000u);
}

__global__ __launch_bounds__(NTHREADS)
void capsule_routing_kernel(const float* __restrict__ x,      // [B,I,A,HW]
                            const float* __restrict__ weight, // [I,A,K]
                            const float* __restrict__ bias,   // [K]
                            float* __restrict__ out)          // [B,K,HW]
{
    __shared__ float sx[NI][NA][P];                 // 4 KB
    __shared__ unsigned short sv[P * NI * SVLD];    // 21.5 KB (bf16 votes)
    __shared__ float slog[P][NI][NOD];              // 2.5 KB
    __shared__ float srt[P][NI][NOD];               // 2.5 KB
    __shared__ float sact[P][NOD][NOA];             // 1.25 KB

    const int bk  = blockIdx.x;                     // 0 .. 2303
    const int b   = bk / (NHW / P);
    const int hw0 = (bk % (NHW / P)) * P;
    const int tid = threadIdx.x;

#define SVIDX(p, i, k) (((p) * NI + (i)) * SVLD + (k))

    // ---- 1) load x slice (float2 over pixel pair), zero logits ----
    if (tid < NI * NA) {
        const int i = tid >> 4;
        const int a = tid & (NA - 1);
        const float2 v = *reinterpret_cast<const float2*>(
            x + (size_t)((b * NI + i) * NA + a) * NHW + hw0);
        sx[i][a][0] = v.x;
        sx[i][a][1] = v.y;
    }
    {
        float* lf = &slog[0][0][0];
        for (int j = tid; j < P * NI * NOD; j += NTHREADS) lf[j] = 0.0f;
    }
    __syncthreads();

    // ---- 2) votes: task = (i, k-quad), float4 weight loads ----
    for (int j = tid; j < NI * (NK / 4); j += NTHREADS) {   // 1280 tasks
        const int i  = j / (NK / 4);
        const int k0 = (j - i * (NK / 4)) * 4;
        const float4* wp = reinterpret_cast<const float4*>(
            weight + (size_t)i * NA * NK + k0);
        float4 a0 = make_float4(0.f, 0.f, 0.f, 0.f);
        float4 a1 = make_float4(0.f, 0.f, 0.f, 0.f);
#pragma unroll
        for (int a = 0; a < NA; ++a) {
            const float4 w4 = wp[a * (NK / 4)];
            const float2 xa = *reinterpret_cast<const float2*>(&sx[i][a][0]);
            a0.x = fmaf(xa.x, w4.x, a0.x); a0.y = fmaf(xa.x, w4.y, a0.y);
            a0.z = fmaf(xa.x, w4.z, a0.z); a0.w = fmaf(xa.x, w4.w, a0.w);
            a1.x = fmaf(xa.y, w4.x, a1.x); a1.y = fmaf(xa.y, w4.y, a1.y);
            a1.z = fmaf(xa.y, w4.z, a1.z); a1.w = fmaf(xa.y, w4.w, a1.w);
        }
        ushort4 s0 = make_ushort4(f2bf(a0.x), f2bf(a0.y), f2bf(a0.z), f2bf(a0.w));
        ushort4 s1 = make_ushort4(f2bf(a1.x), f2bf(a1.y), f2bf(a1.z), f2bf(a1.w));
        *reinterpret_cast<ushort4*>(&sv[SVIDX(0, i, k0)]) = s0;
        *reinterpret_cast<ushort4*>(&sv[SVIDX(1, i, k0)]) = s1;
    }
    __syncthreads();

    // ---- 3) dynamic routing ----
    for (int it = 0; it < NROUT; ++it) {
        // softmax over od per (p, i): 64 rows
        if (tid < P * NI) {
            const int p = tid >> 5;
            const int i = tid & 31;
            float m = slog[p][i][0];
#pragma unroll
            for (int od = 1; od < NOD; ++od) m = fmaxf(m, slog[p][i][od]);
            float e[NOD];
            float s = 0.0f;
#pragma unroll
            for (int od = 0; od < NOD; ++od) {
                e[od] = __expf(slog[p][i][od] - m);
                s += e[od];
            }
            const float inv = 1.0f / s;
#pragma unroll
            for (int od = 0; od < NOD; ++od) srt[p][i][od] = e[od] * inv;
        }
        __syncthreads();

        // preact + fused squash: one (p,k) per thread, 320 active
        if (tid < P * NK) {
            const int p  = tid / NK;
            const int k  = tid - p * NK;
            const int od = k >> 4;
            const int oa = k & (NOA - 1);
            float acc = bias[k];
            const unsigned short* svp = &sv[SVIDX(p, 0, k)];
#pragma unroll
            for (int i = 0; i < NI; ++i)
                acc = fmaf(srt[p][i][od], bf2f(svp[i * SVLD]), acc);
            float ss = acc * acc;
#pragma unroll
            for (int m = 1; m < NOA; m <<= 1)
                ss += __shfl_xor(ss, m, NOA);
            const float scale = sqrtf(ss) / (1.0f + ss);
            sact[p][od][oa] = acc * scale;
        }
        __syncthreads();

        if (it < NROUT - 1) {
            // logits[p][i][od] += sum_oa votes * act ; uint4 = 8 bf16 per read
            for (int j = tid; j < P * NI * NOD; j += NTHREADS) {  // 640 tasks
                const int p  = j / (NI * NOD);
                const int r  = j - p * (NI * NOD);
                const int od = r >> 5;
                const int i  = r & 31;
                const uint4 d0 = *reinterpret_cast<const uint4*>(
                    &sv[SVIDX(p, i, od * NOA)]);
                const uint4 d1 = *reinterpret_cast<const uint4*>(
                    &sv[SVIDX(p, i, od * NOA + 8)]);
                const float* ap = &sact[p][od][0];
                float acc;
                acc  = bf_lo(d0.x) * ap[0];
                acc = fmaf(bf_hi(d0.x), ap[1], acc);
                acc = fmaf(bf_lo(d0.y), ap[2], acc);
                acc = fmaf(bf_hi(d0.y), ap[3], acc);
                acc = fmaf(bf_lo(d0.z), ap[4], acc);
                acc = fmaf(bf_hi(d0.z), ap[5], acc);
                acc = fmaf(bf_lo(d0.w), ap[6], acc);
                acc = fmaf(bf_hi(d0.w), ap[7], acc);
                acc = fmaf(bf_lo(d1.x), ap[8], acc);
                acc = fmaf(bf_hi(d1.x), ap[9], acc);
                acc = fmaf(bf_lo(d1.y), ap[10], acc);
                acc = fmaf(bf_hi(d1.y), ap[11], acc);
                acc = fmaf(bf_lo(d1.z), ap[12], acc);
                acc = fmaf(bf_hi(d1.z), ap[13], acc);
                acc = fmaf(bf_lo(d1.w), ap[14], acc);
                acc = fmaf(bf_hi(d1.w), ap[15], acc);
                slog[p][i][od] += acc;
            }
            __syncthreads();
        }
    }

    // ---- 4) write activation ----
    __syncthreads();
    if (tid < NK) {
        const int od = tid >> 4;
        const int oa = tid & (NOA - 1);
        const float2 v = make_float2(sact[0][od][oa], sact[1][od][oa]);
        *reinterpret_cast<float2*>(out + (size_t)(b * NK + tid) * NHW + hw0) = v;
    }
}

extern "C" void kernel_launch(void* const* d_in, const int* in_sizes, int n_in,
                              void* d_out, int out_size, void* d_ws, size_t ws_size,
                              hipStream_t stream) {
    const float* x      = (const float*)d_in[0];
    const float* weight = (const float*)d_in[1];
    const float* bias   = (const float*)d_in[2];
    float* out          = (float*)d_out;

    const int nblocks = NB * (NHW / P);   // 2304
    capsule_routing_kernel<<<nblocks, NTHREADS, 0, stream>>>(x, weight, bias, out);
}